// Round 7
// baseline (673.246 us; speedup 1.0000x reference)
//
#include <hip/hip_runtime.h>
#include <hip/hip_fp16.h>
#include <math.h>

#define NN 100000
#define NE 1000000
#define IND 256
#define HD  128
#define NPB 64           // nodes per block in layer kernel
#define FNPB 64          // nodes per block in final kernel
#define INPB 64          // nodes per block in init kernel
#define NBLK_SCAN 98     // ceil(NN/1024)
#define ECAP 1536        // staged edges per block (avg 640, tail-safe + guarded)
#define NLBLK ((NN + NPB - 1) / NPB)     // 1563
#define H16_BYTES ((size_t)NN * HD * 2)  // 25,600,000

typedef _Float16 f16x8 __attribute__((ext_vector_type(8)));
typedef float f32x4 __attribute__((ext_vector_type(4)));

union U16 { uint4 u; __half2 h2[4]; __half h[8]; f16x8 v; };

// ---------------- CSR build ----------------

__global__ __launch_bounds__(256) void k_deg(const int* __restrict__ dst,
                                             int* __restrict__ deg) {
    int e = blockIdx.x * 256 + threadIdx.x;
    if (e < NE) atomicAdd(&deg[dst[e]], 1);
}

__global__ __launch_bounds__(1024) void k_scan1(const int* __restrict__ deg,
                                                int* __restrict__ rowp,
                                                int* __restrict__ bsums,
                                                float* __restrict__ dinv) {
    __shared__ int s[1024];
    int t = threadIdx.x;
    int i = blockIdx.x * 1024 + t;
    int v = (i < NN) ? deg[i] : 0;
    if (i < NN) dinv[i] = rsqrtf((float)(v + 1));  // +1 self-loop
    s[t] = v;
    __syncthreads();
    for (int off = 1; off < 1024; off <<= 1) {
        int u = (t >= off) ? s[t - off] : 0;
        __syncthreads();
        s[t] += u;
        __syncthreads();
    }
    if (i < NN) rowp[i] = s[t] - v;
    if (t == 1023) bsums[blockIdx.x] = s[1023];
}

__global__ __launch_bounds__(128) void k_scan2(int* __restrict__ bsums) {
    __shared__ int s[128];
    int t = threadIdx.x;
    int v = (t < NBLK_SCAN) ? bsums[t] : 0;
    s[t] = v;
    __syncthreads();
    for (int off = 1; off < 128; off <<= 1) {
        int u = (t >= off) ? s[t - off] : 0;
        __syncthreads();
        s[t] += u;
        __syncthreads();
    }
    if (t < NBLK_SCAN) bsums[t] = s[t] - v;
}

__global__ __launch_bounds__(1024) void k_scan3(int* __restrict__ rowp,
                                                const int* __restrict__ bsums) {
    int i = blockIdx.x * 1024 + threadIdx.x;
    if (i < NN) rowp[i] += bsums[i >> 10];
    if (i == 0) rowp[NN] = NE;
}

__global__ __launch_bounds__(256) void k_fill(const int* __restrict__ src,
                                              const int* __restrict__ dst,
                                              const int* __restrict__ rowp,
                                              int* __restrict__ fill,
                                              int* __restrict__ col) {
    int e = blockIdx.x * 256 + threadIdx.x;
    if (e < NE) {
        int d = dst[e];
        int pos = rowp[d] + atomicAdd(&fill[d], 1);
        col[pos] = src[e];
    }
}

// ---------------- weight fragment pre-pack (all 12 matrices) ----------------
// KS=4 layout: wf[m][((nt*4+ks)*64+lane)*8+j] = f16(W'[ks*32+(lane>>4)*8+j][nt*16+(lane&15)])
// For m<8 (conv layers) the residual is folded in: W' = beta*W + (1-beta)*I.
// blocks 176..207: W1 [256,128], KS=8 into w1f.

__global__ __launch_bounds__(256) void k_wfrag(const float* __restrict__ cw,
                                               const float* __restrict__ W2,
                                               const float* __restrict__ Wv,
                                               const float* __restrict__ Wt,
                                               const float* __restrict__ W1,
                                               __half* __restrict__ wf,
                                               __half* __restrict__ w1f) {
    int bid = blockIdx.x;
    if (bid < 176) {
        int m = bid >> 4;     // matrix 0..10
        int blk = bid & 15;
        const float* W = (m < 8) ? (cw + (size_t)m * HD * HD)
                                 : (m == 8 ? W2 : (m == 9 ? Wv : Wt));
        int i = (blk * 256 + threadIdx.x) * 4;   // element index k*128+col
        float4 v = *(const float4*)&W[i];
        int k = i >> 7, col0 = i & 127;
        float vv[4] = {v.x, v.y, v.z, v.w};
        float beta = 1.f, omb = 0.f;
        if (m < 8) {
            beta = logf(0.5f / (float)(m + 1) + 1.0f);
            omb = 1.f - beta;
        }
        __half* dstm = wf + (size_t)m * HD * HD;
        int ks = k >> 5, laneK = ((k >> 3) & 3) * 16, j = k & 7;
#pragma unroll
        for (int t = 0; t < 4; t++) {
            int col = col0 + t;
            float val = beta * vv[t] + ((k == col) ? omb : 0.f);
            int nt = col >> 4;
            int lane = laneK + (col & 15);
            dstm[((nt * 4 + ks) * 64 + lane) * 8 + j] = __float2half(val);
        }
    } else {
        int blk = bid - 176;  // 0..31
        int i = (blk * 256 + threadIdx.x) * 4;   // k*128+col, total 32768
        float4 v = *(const float4*)&W1[i];
        int k = i >> 7, col0 = i & 127;
        float vv[4] = {v.x, v.y, v.z, v.w};
        int ks = k >> 5, laneK = ((k >> 3) & 3) * 16, j = k & 7;
#pragma unroll
        for (int t = 0; t < 4; t++) {
            int col = col0 + t;
            int nt = col >> 4;
            int lane = laneK + (col & 15);
            w1f[((nt * 8 + ks) * 64 + lane) * 8 + j] = __float2half(vv[t]);
        }
    }
}

// ---------------- initial transform (MFMA): h0 = relu(x@W1+b1) f16, g0 = dinv*h0 f16 ----

__global__ __launch_bounds__(256) void k_init(const float* __restrict__ x,
                                              const __half* __restrict__ w1f,
                                              const float* __restrict__ b1,
                                              const float* __restrict__ dinv,
                                              __half* __restrict__ h0h,
                                              __half* __restrict__ g0) {
    __shared__ char lds[32768];     // xs (swizzled f16 64x256), later hb/gb
    int tid = threadIdx.x;
    int nb = blockIdx.x * INPB;
    int wv = tid >> 6, lane = tid & 63;

    // stage x -> f16 swizzled (rows of 512B)
#pragma unroll
    for (int it = 0; it < 8; it++) {
        int c = it * 256 + tid;          // chunk of 8 floats: 64 rows x 32 chunks
        int row = c >> 5, k8 = c & 31;
        int gn = nb + row;
        float4 a = make_float4(0.f, 0.f, 0.f, 0.f), b = a;
        if (gn < NN) {
            a = *(const float4*)&x[(size_t)gn * IND + k8 * 8];
            b = *(const float4*)&x[(size_t)gn * IND + k8 * 8 + 4];
        }
        U16 p;
        p.h[0] = __float2half(a.x); p.h[1] = __float2half(a.y);
        p.h[2] = __float2half(a.z); p.h[3] = __float2half(a.w);
        p.h[4] = __float2half(b.x); p.h[5] = __float2half(b.y);
        p.h[6] = __float2half(b.z); p.h[7] = __float2half(b.w);
        int byte = (row * 512 + k8 * 16) ^ ((row & 7) << 4);
        *(uint4*)(lds + byte) = p.u;
    }
    __syncthreads();

    // A-frags: wave = row-tile
    int arow = wv * 16 + (lane & 15);
    f16x8 a[8];
#pragma unroll
    for (int ks = 0; ks < 8; ks++) {
        int byte = (arow * 512 + ks * 64 + (lane >> 4) * 16) ^ ((arow & 7) << 4);
        U16 r; r.u = *(const uint4*)(lds + byte);
        a[ks] = r.v;
    }
    __syncthreads();   // all waves done reading xs before epilogue overwrites

    __half* hb = (__half*)lds;            // 64x128 f16 linear
    __half* gbuf = (__half*)(lds + 16384);
    const uint4* bf = (const uint4*)w1f;

#pragma unroll
    for (int nt = 0; nt < 8; nt++) {
        f32x4 acc = {0.f, 0.f, 0.f, 0.f};
#pragma unroll
        for (int ks = 0; ks < 8; ks++) {
            U16 bw; bw.u = bf[(nt * 8 + ks) * 64 + lane];
            acc = __builtin_amdgcn_mfma_f32_16x16x32_f16(a[ks], bw.v, acc, 0, 0, 0);
        }
        int colb = nt * 16 + (lane & 15);
        float bias = b1[colb];
#pragma unroll
        for (int r = 0; r < 4; r++) {
            int row = wv * 16 + (lane >> 4) * 4 + r;
            int gn = nb + row;
            float dv = (gn < NN) ? dinv[gn] : 0.f;
            float v = fmaxf(acc[r] + bias, 0.f);
            hb[row * HD + colb] = __float2half(v);
            gbuf[row * HD + colb] = __float2half(dv * v);
        }
    }
    __syncthreads();

    // coalesced copy-out
#pragma unroll
    for (int it = 0; it < 4; it++) {
        int c = it * 256 + tid;          // 1024 chunks of 16B per buffer
        int row = c >> 4;
        if (nb + row < NN) {
            *(uint4*)((char*)h0h + (size_t)nb * 256 + c * 16) = *(uint4*)((char*)hb + c * 16);
            *(uint4*)((char*)g0 + (size_t)nb * 256 + c * 16) = *(uint4*)((char*)gbuf + c * 16);
        }
    }
}

// ---------------- GCNII layer ----------------
// gather: one 16-lane group owns one node; col slice staged in LDS; work-stealing
// over 64 nodes; 8-deep unrolled independent row loads.
// GEMM: h = relu(comb @ W') with W' = (1-b)I + bW pre-folded. Wave-private row-tile.
// OUT_MODE 0: gOut = f16(dinv*h) contiguous   OUT_MODE 1: hOut = f16 h, 512B-strided

template <int OUT_MODE>
__global__ __launch_bounds__(256) void k_layer(const __half2* __restrict__ gIn,
                                               __half* __restrict__ gOutH,
                                               __half* __restrict__ hOut7,
                                               const __half2* __restrict__ h0,
                                               const float* __restrict__ dinv,
                                               const int* __restrict__ rowp,
                                               const int* __restrict__ col,
                                               const __half* __restrict__ wfL) {
    __shared__ __half csh[NPB * HD];    // 16 KB: comb f16, swizzled; reused for output
    __shared__ int sCol[ECAP];          // 6 KB staged col indices
    __shared__ int sRowp[NPB + 1];
    __shared__ int sCtr;
    int tid = threadIdx.x;
    int nb = blockIdx.x * NPB;
    int lane = tid & 63;
    int sub = lane & 15;                // lane within 16-lane group
    const uint4* g4 = (const uint4*)gIn;   // 16 chunks of 16B per row
    const uint4* h4 = (const uint4*)h0;

    if (tid == 0) sCtr = 0;
    if (tid <= NPB) {
        int idx = nb + tid;
        sRowp[tid] = rowp[idx < NN ? idx : NN];
    }
    __syncthreads();
    int base = sRowp[0];
    int total = sRowp[NPB] - base;
    int stct = total < ECAP ? total : ECAP;
    for (int i = tid; i < stct; i += 256) sCol[i] = col[base + i];
    __syncthreads();

    while (true) {
        int nl;
        if (sub == 0) nl = atomicAdd(&sCtr, 1);
        nl = __shfl(nl, lane & 48);     // broadcast from group leader
        if (nl >= NPB) break;
        int n = nb + nl;
        U16 p;
        if (n < NN) {
            int beg = sRowp[nl] - base, end = sRowp[nl + 1] - base;

            // self-loop init
            float acc[8];
            {
                U16 v; v.u = g4[(size_t)n * 16 + sub];
#pragma unroll
                for (int q = 0; q < 4; q++) {
                    float2 f = __half22float2(v.h2[q]);
                    acc[2 * q] = f.x; acc[2 * q + 1] = f.y;
                }
            }

            int e = beg;
            for (; e + 8 <= end; e += 8) {
                int cc[8];
#pragma unroll
                for (int u = 0; u < 8; u++)
                    cc[u] = (e + u < ECAP) ? sCol[e + u] : col[base + e + u];
                U16 av[8];
#pragma unroll
                for (int u = 0; u < 8; u++) av[u].u = g4[(size_t)cc[u] * 16 + sub];
#pragma unroll
                for (int u = 0; u < 8; u++)
#pragma unroll
                    for (int q = 0; q < 4; q++) {
                        float2 f = __half22float2(av[u].h2[q]);
                        acc[2 * q] += f.x; acc[2 * q + 1] += f.y;
                    }
            }
            if (e + 4 <= end) {
                int cc[4];
#pragma unroll
                for (int u = 0; u < 4; u++)
                    cc[u] = (e + u < ECAP) ? sCol[e + u] : col[base + e + u];
                U16 av[4];
#pragma unroll
                for (int u = 0; u < 4; u++) av[u].u = g4[(size_t)cc[u] * 16 + sub];
#pragma unroll
                for (int u = 0; u < 4; u++)
#pragma unroll
                    for (int q = 0; q < 4; q++) {
                        float2 f = __half22float2(av[u].h2[q]);
                        acc[2 * q] += f.x; acc[2 * q + 1] += f.y;
                    }
                e += 4;
            }
            if (e + 2 <= end) {
                int c0 = (e < ECAP) ? sCol[e] : col[base + e];
                int c1 = (e + 1 < ECAP) ? sCol[e + 1] : col[base + e + 1];
                U16 a0, a1;
                a0.u = g4[(size_t)c0 * 16 + sub];
                a1.u = g4[(size_t)c1 * 16 + sub];
#pragma unroll
                for (int q = 0; q < 4; q++) {
                    float2 f0 = __half22float2(a0.h2[q]);
                    float2 f1 = __half22float2(a1.h2[q]);
                    acc[2 * q] += f0.x + f1.x;
                    acc[2 * q + 1] += f0.y + f1.y;
                }
                e += 2;
            }
            if (e < end) {
                int c0 = (e < ECAP) ? sCol[e] : col[base + e];
                U16 a0; a0.u = g4[(size_t)c0 * 16 + sub];
#pragma unroll
                for (int q = 0; q < 4; q++) {
                    float2 f0 = __half22float2(a0.h2[q]);
                    acc[2 * q] += f0.x; acc[2 * q + 1] += f0.y;
                }
            }

            float dv = dinv[n];
            U16 hv; hv.u = h4[(size_t)n * 16 + sub];
#pragma unroll
            for (int q = 0; q < 4; q++) {
                float2 hf = __half22float2(hv.h2[q]);
                float c0 = 0.9f * dv * acc[2 * q]     + 0.1f * hf.x;
                float c1 = 0.9f * dv * acc[2 * q + 1] + 0.1f * hf.y;
                p.h2[q] = __float22half2_rn(make_float2(c0, c1));
            }
        } else {
            p.u = make_uint4(0, 0, 0, 0);
        }
        int fbyte = (nl * 256 + sub * 16) ^ ((nl & 7) << 4);
        *(uint4*)((char*)csh + fbyte) = p.u;
    }
    __syncthreads();

    // MFMA GEMM: wave-private row-tile (4 waves x 16 rows), 8 col-tiles each
    int wave = tid >> 6;
    int arow = wave * 16 + (lane & 15);
    f16x8 a[4];
#pragma unroll
    for (int ks = 0; ks < 4; ks++) {
        int byte = (arow * 256 + ks * 64 + (lane >> 4) * 16) ^ ((arow & 7) << 4);
        U16 r; r.u = *(const uint4*)((const char*)csh + byte);
        a[ks] = r.v;
    }
    // no barrier: each wave reads/writes only its own 16 rows of csh

    const uint4* bf = (const uint4*)wfL;
#pragma unroll
    for (int nt = 0; nt < 8; nt++) {
        f32x4 acc = {0.f, 0.f, 0.f, 0.f};
#pragma unroll
        for (int ks = 0; ks < 4; ks++) {
            U16 bw; bw.u = bf[(nt * 4 + ks) * 64 + lane];
            acc = __builtin_amdgcn_mfma_f32_16x16x32_f16(a[ks], bw.v, acc, 0, 0, 0);
        }
        int colb = nt * 16 + (lane & 15);
#pragma unroll
        for (int r = 0; r < 4; r++) {
            int row = wave * 16 + (lane >> 4) * 4 + r;
            int gn = nb + row;
            float v = fmaxf(acc[r], 0.f);
            if (OUT_MODE == 0) {
                float dv = (gn < NN) ? dinv[gn] : 0.f;
                csh[row * HD + colb] = __float2half(dv * v);
            } else {
                csh[row * HD + colb] = __float2half(v);
            }
        }
    }
    __syncthreads();
    // coalesced copy-out: 64 rows x 256B = 1024 chunks of 16B
    if (OUT_MODE == 0) {
#pragma unroll
        for (int it = 0; it < 4; it++) {
            int c = it * 256 + tid;
            int row = c >> 4;
            if (nb + row < NN)
                *(uint4*)((char*)gOutH + (size_t)nb * 256 + c * 16) =
                    *(uint4*)((char*)csh + c * 16);
        }
    } else {
        // strided: row gn occupies first 256B of a 512B slot (1:1 with k_final blocks)
#pragma unroll
        for (int it = 0; it < 4; it++) {
            int c = it * 256 + tid;
            int row = c >> 4;
            if (nb + row < NN)
                *(uint4*)((char*)hOut7 + ((size_t)(nb + row) * 512 + (c & 15) * 16)) =
                    *(uint4*)((char*)csh + c * 16);
        }
    }
}

// ---------------- final (MFMA): out = h@W2+b2; vis = relu(out@Wv+bv); txt = relu(out@Wt+bt)
// hIn: f16 rows strided at 512B (first 256B of each slot), co-located with `out`.

__global__ __launch_bounds__(256) void k_final(const __half* __restrict__ hIn,
                                               const __half* __restrict__ wf,
                                               const float* __restrict__ b2,
                                               const float* __restrict__ bv,
                                               const float* __restrict__ bt,
                                               float* __restrict__ out,
                                               float* __restrict__ vis,
                                               float* __restrict__ txt) {
    __shared__ __half hs[FNPB * HD];  // 16 KB, XOR-swizzled rows
    __shared__ __half os[FNPB * HD];  // 16 KB, XOR-swizzled rows
    int tid = threadIdx.x;
    int nb = blockIdx.x * FNPB;
    int wave = tid >> 6, lane = tid & 63;

    // stage h rows (f16, strided in global) -> swizzled LDS
#pragma unroll
    for (int it = 0; it < 4; it++) {
        int idx = it * 256 + tid;            // 16B chunk; 64 rows x 16 chunks
        int row = idx >> 4, c8 = idx & 15;
        int gn = nb + row;
        uint4 p = make_uint4(0, 0, 0, 0);
        if (gn < NN)
            p = *(const uint4*)((const char*)hIn + (size_t)gn * 512 + c8 * 16);
        int byte = (row * 256 + c8 * 16) ^ ((row & 7) << 4);
        *(uint4*)((char*)hs + byte) = p;
    }
    __syncthreads();

    const uint4* bf2 = (const uint4*)(wf + (size_t)8 * HD * HD);
    const uint4* bfv = (const uint4*)(wf + (size_t)9 * HD * HD);
    const uint4* bft = (const uint4*)(wf + (size_t)10 * HD * HD);

    int arow = wave * 16 + (lane & 15);
    int kb = (lane >> 4) * 8;

    // A-frags from hs
    f16x8 a[4];
#pragma unroll
    for (int ks = 0; ks < 4; ks++) {
        int byte = (arow * 256 + (ks * 32 + kb) * 2) ^ ((arow & 7) << 4);
        U16 r; r.u = *(const uint4*)((const char*)hs + byte);
        a[ks] = r.v;
    }

    // GEMM1: out = h@W2 + b2 ; also write f16 copy into os
#pragma unroll
    for (int nt = 0; nt < 8; nt++) {
        f32x4 acc = {0.f, 0.f, 0.f, 0.f};
#pragma unroll
        for (int ks = 0; ks < 4; ks++) {
            U16 bw; bw.u = bf2[(nt * 4 + ks) * 64 + lane];
            acc = __builtin_amdgcn_mfma_f32_16x16x32_f16(a[ks], bw.v, acc, 0, 0, 0);
        }
        int c = nt * 16 + (lane & 15);
        float bias = b2[c];
#pragma unroll
        for (int r = 0; r < 4; r++) {
            int lrow = wave * 16 + (lane >> 4) * 4 + r;
            float val = acc[r] + bias;
            int gn = nb + lrow;
            if (gn < NN) out[(size_t)gn * HD + c] = val;
            int byte = (lrow * 256 + c * 2) ^ ((lrow & 7) << 4);
            *(__half*)((char*)os + byte) = __float2half(val);
        }
    }
    __syncthreads();

    // A-frags from os
    f16x8 ao[4];
#pragma unroll
    for (int ks = 0; ks < 4; ks++) {
        int byte = (arow * 256 + (ks * 32 + kb) * 2) ^ ((arow & 7) << 4);
        U16 r; r.u = *(const uint4*)((const char*)os + byte);
        ao[ks] = r.v;
    }

    // GEMM2: vis = relu(out@Wv+bv); GEMM3: txt = relu(out@Wt+bt)
#pragma unroll
    for (int nt = 0; nt < 8; nt++) {
        f32x4 accv = {0.f, 0.f, 0.f, 0.f};
        f32x4 acct = {0.f, 0.f, 0.f, 0.f};
#pragma unroll
        for (int ks = 0; ks < 4; ks++) {
            U16 bwv; bwv.u = bfv[(nt * 4 + ks) * 64 + lane];
            U16 bwt; bwt.u = bft[(nt * 4 + ks) * 64 + lane];
            accv = __builtin_amdgcn_mfma_f32_16x16x32_f16(ao[ks], bwv.v, accv, 0, 0, 0);
            acct = __builtin_amdgcn_mfma_f32_16x16x32_f16(ao[ks], bwt.v, acct, 0, 0, 0);
        }
        int c = nt * 16 + (lane & 15);
        float biasv = bv[c], biast = bt[c];
#pragma unroll
        for (int r = 0; r < 4; r++) {
            int lrow = wave * 16 + (lane >> 4) * 4 + r;
            int gn = nb + lrow;
            if (gn < NN) {
                vis[(size_t)gn * HD + c] = fmaxf(accv[r] + biasv, 0.f);
                txt[(size_t)gn * HD + c] = fmaxf(acct[r] + biast, 0.f);
            }
        }
    }
}

// ---------------- launch ----------------

extern "C" void kernel_launch(void* const* d_in, const int* in_sizes, int n_in,
                              void* d_out, int out_size, void* d_ws, size_t ws_size,
                              hipStream_t stream) {
    (void)in_sizes; (void)n_in; (void)out_size; (void)ws_size;

    const float* x    = (const float*)d_in[0];
    const int*   edge = (const int*)d_in[1];   // [2,E]: src then dst
    const float* W1   = (const float*)d_in[2];
    const float* b1   = (const float*)d_in[3];
    const float* cw   = (const float*)d_in[4]; // [8,128,128]
    const float* W2   = (const float*)d_in[5];
    const float* b2   = (const float*)d_in[6];
    const float* Wv   = (const float*)d_in[7];
    const float* bv   = (const float*)d_in[8];
    const float* Wt   = (const float*)d_in[9];
    const float* bt   = (const float*)d_in[10];

    const int* esrc = edge;
    const int* edst = edge + NE;

    // d_out regions: [0]=h7 (f16, 512B-strided) then `out`; [1]=h0(f16) then vis;
    // [2]=g ping-pong (2 x f16) then txt
    float* out0 = (float*)d_out;
    float* reg1 = out0 + (size_t)NN * HD;
    float* reg2 = reg1 + (size_t)NN * HD;

    __half* h0h = (__half*)reg1;
    __half* ga  = (__half*)reg2;
    __half* gb  = (__half*)((char*)reg2 + H16_BYTES);

    // workspace layout
    char* ws = (char*)d_ws;
    int*   deg_i = (int*)(ws + 0);          // N ints
    int*   fill  = (int*)(ws + 400000);     // N ints
    int*   rowp  = (int*)(ws + 800000);     // N+1 ints
    int*   bsums = (int*)(ws + 1200128);    // 128 ints
    int*   col   = (int*)(ws + 1200640);    // E ints
    float* dinv  = (float*)(ws + 5200640);  // N floats
    __half* wf   = (__half*)(ws + 5600640); // 11 * 128*128 halfs = 360448 B
    __half* w1f  = (__half*)(ws + 5961088); // 256*128 halfs = 65536 B

    hipMemsetAsync(ws, 0, 800000, stream);  // deg_i + fill

    k_deg<<<(NE + 255) / 256, 256, 0, stream>>>(edst, deg_i);
    k_scan1<<<NBLK_SCAN, 1024, 0, stream>>>(deg_i, rowp, bsums, dinv);
    k_scan2<<<1, 128, 0, stream>>>(bsums);
    k_scan3<<<NBLK_SCAN, 1024, 0, stream>>>(rowp, bsums);
    k_fill<<<(NE + 255) / 256, 256, 0, stream>>>(esrc, edst, rowp, fill, col);
    k_wfrag<<<208, 256, 0, stream>>>(cw, W2, Wv, Wt, W1, wf, w1f);

    k_init<<<(NN + INPB - 1) / INPB, 256, 0, stream>>>(x, w1f, b1, dinv, h0h, ga);

    // layers 0..6: f16 ping-pong (l even: ga->gb, odd: gb->ga). After l=6, g in gb.
    for (int l = 0; l < 7; l++) {
        const __half* gi = (l & 1) ? gb : ga;
        __half*       go = (l & 1) ? ga : gb;
        k_layer<0><<<NLBLK, 256, 0, stream>>>((const __half2*)gi, go,
                                              (__half*)nullptr, (const __half2*)h0h,
                                              dinv, rowp, col,
                                              wf + (size_t)l * HD * HD);
    }
    // layer 7: gb -> f16 h (strided) in region0
    k_layer<1><<<NLBLK, 256, 0, stream>>>((const __half2*)gb, (__half*)nullptr,
                                          (__half*)out0, (const __half2*)h0h,
                                          dinv, rowp, col,
                                          wf + (size_t)7 * HD * HD);

    k_final<<<(NN + FNPB - 1) / FNPB, 256, 0, stream>>>((const __half*)out0, wf,
                                                        b2, bv, bt,
                                                        out0, reg1, reg2);
}

// Round 8
// 657.320 us; speedup vs baseline: 1.0242x; 1.0242x over previous
//
#include <hip/hip_runtime.h>
#include <hip/hip_fp16.h>
#include <math.h>
#include <type_traits>

#define NN 100000
#define NE 1000000
#define IND 256
#define HD  128
#define NPB 32           // nodes per block in layer kernel (divides NN exactly)
#define FNPB 64          // nodes per block in final kernel
#define INPB 64          // nodes per block in init kernel
#define NBLK_SCAN 98     // ceil(NN/1024)
#define ECAP 768         // staged edges per block (avg 320, tail-safe + guarded fallback)
#define H16_BYTES ((size_t)NN * HD * 2)  // 25,600,000

typedef _Float16 f16x8 __attribute__((ext_vector_type(8)));
typedef float f32x4 __attribute__((ext_vector_type(4)));

union U16 { uint4 u; __half2 h2[4]; __half h[8]; f16x8 v; };

// ---------------- CSR build ----------------

__global__ __launch_bounds__(256) void k_deg(const int* __restrict__ dst,
                                             int* __restrict__ deg) {
    int e = blockIdx.x * 256 + threadIdx.x;
    if (e < NE) atomicAdd(&deg[dst[e]], 1);
}

__global__ __launch_bounds__(1024) void k_scan1(const int* __restrict__ deg,
                                                int* __restrict__ rowp,
                                                int* __restrict__ bsums,
                                                float* __restrict__ dinv) {
    __shared__ int s[1024];
    int t = threadIdx.x;
    int i = blockIdx.x * 1024 + t;
    int v = (i < NN) ? deg[i] : 0;
    if (i < NN) dinv[i] = rsqrtf((float)(v + 1));  // +1 self-loop
    s[t] = v;
    __syncthreads();
    for (int off = 1; off < 1024; off <<= 1) {
        int u = (t >= off) ? s[t - off] : 0;
        __syncthreads();
        s[t] += u;
        __syncthreads();
    }
    if (i < NN) rowp[i] = s[t] - v;
    if (t == 1023) bsums[blockIdx.x] = s[1023];
}

__global__ __launch_bounds__(128) void k_scan2(int* __restrict__ bsums) {
    __shared__ int s[128];
    int t = threadIdx.x;
    int v = (t < NBLK_SCAN) ? bsums[t] : 0;
    s[t] = v;
    __syncthreads();
    for (int off = 1; off < 128; off <<= 1) {
        int u = (t >= off) ? s[t - off] : 0;
        __syncthreads();
        s[t] += u;
        __syncthreads();
    }
    if (t < NBLK_SCAN) bsums[t] = s[t] - v;
}

__global__ __launch_bounds__(1024) void k_scan3(int* __restrict__ rowp,
                                                const int* __restrict__ bsums) {
    int i = blockIdx.x * 1024 + threadIdx.x;
    if (i < NN) rowp[i] += bsums[i >> 10];
    if (i == 0) rowp[NN] = NE;
}

__global__ __launch_bounds__(256) void k_fill(const int* __restrict__ src,
                                              const int* __restrict__ dst,
                                              const int* __restrict__ rowp,
                                              int* __restrict__ fill,
                                              int* __restrict__ col) {
    int e = blockIdx.x * 256 + threadIdx.x;
    if (e < NE) {
        int d = dst[e];
        int pos = rowp[d] + atomicAdd(&fill[d], 1);
        col[pos] = src[e];
    }
}

// ---------------- weight fragment pre-pack (all 12 matrices) ----------------
// KS=4 layout: wf[m][((nt*4+ks)*64+lane)*8+j] = f16(W'[ks*32+(lane>>4)*8+j][nt*16+(lane&15)])
// For m<8 (conv layers) the residual is folded in: W' = beta*W + (1-beta)*I.
// blocks 176..207: W1 [256,128], KS=8 into w1f.

__global__ __launch_bounds__(256) void k_wfrag(const float* __restrict__ cw,
                                               const float* __restrict__ W2,
                                               const float* __restrict__ Wv,
                                               const float* __restrict__ Wt,
                                               const float* __restrict__ W1,
                                               __half* __restrict__ wf,
                                               __half* __restrict__ w1f) {
    int bid = blockIdx.x;
    if (bid < 176) {
        int m = bid >> 4;     // matrix 0..10
        int blk = bid & 15;
        const float* W = (m < 8) ? (cw + (size_t)m * HD * HD)
                                 : (m == 8 ? W2 : (m == 9 ? Wv : Wt));
        int i = (blk * 256 + threadIdx.x) * 4;   // element index k*128+col
        float4 v = *(const float4*)&W[i];
        int k = i >> 7, col0 = i & 127;
        float vv[4] = {v.x, v.y, v.z, v.w};
        float beta = 1.f, omb = 0.f;
        if (m < 8) {
            beta = logf(0.5f / (float)(m + 1) + 1.0f);
            omb = 1.f - beta;
        }
        __half* dstm = wf + (size_t)m * HD * HD;
        int ks = k >> 5, laneK = ((k >> 3) & 3) * 16, j = k & 7;
#pragma unroll
        for (int t = 0; t < 4; t++) {
            int col = col0 + t;
            float val = beta * vv[t] + ((k == col) ? omb : 0.f);
            int nt = col >> 4;
            int lane = laneK + (col & 15);
            dstm[((nt * 4 + ks) * 64 + lane) * 8 + j] = __float2half(val);
        }
    } else {
        int blk = bid - 176;  // 0..31
        int i = (blk * 256 + threadIdx.x) * 4;   // k*128+col, total 32768
        float4 v = *(const float4*)&W1[i];
        int k = i >> 7, col0 = i & 127;
        float vv[4] = {v.x, v.y, v.z, v.w};
        int ks = k >> 5, laneK = ((k >> 3) & 3) * 16, j = k & 7;
#pragma unroll
        for (int t = 0; t < 4; t++) {
            int col = col0 + t;
            int nt = col >> 4;
            int lane = laneK + (col & 15);
            w1f[((nt * 8 + ks) * 64 + lane) * 8 + j] = __float2half(vv[t]);
        }
    }
}

// ---------------- initial transform (MFMA): h0 = relu(x@W1+b1) f16, g0 = dinv*h0 f16 ----

__global__ __launch_bounds__(256) void k_init(const float* __restrict__ x,
                                              const __half* __restrict__ w1f,
                                              const float* __restrict__ b1,
                                              const float* __restrict__ dinv,
                                              __half* __restrict__ h0h,
                                              __half* __restrict__ g0) {
    __shared__ char lds[32768];     // xs (swizzled f16 64x256), later hb/gb
    int tid = threadIdx.x;
    int nb = blockIdx.x * INPB;
    int wv = tid >> 6, lane = tid & 63;

    // stage x -> f16 swizzled (rows of 512B)
#pragma unroll
    for (int it = 0; it < 8; it++) {
        int c = it * 256 + tid;          // chunk of 8 floats: 64 rows x 32 chunks
        int row = c >> 5, k8 = c & 31;
        int gn = nb + row;
        float4 a = make_float4(0.f, 0.f, 0.f, 0.f), b = a;
        if (gn < NN) {
            a = *(const float4*)&x[(size_t)gn * IND + k8 * 8];
            b = *(const float4*)&x[(size_t)gn * IND + k8 * 8 + 4];
        }
        U16 p;
        p.h[0] = __float2half(a.x); p.h[1] = __float2half(a.y);
        p.h[2] = __float2half(a.z); p.h[3] = __float2half(a.w);
        p.h[4] = __float2half(b.x); p.h[5] = __float2half(b.y);
        p.h[6] = __float2half(b.z); p.h[7] = __float2half(b.w);
        int byte = (row * 512 + k8 * 16) ^ ((row & 7) << 4);
        *(uint4*)(lds + byte) = p.u;
    }
    __syncthreads();

    // A-frags: wave = row-tile
    int arow = wv * 16 + (lane & 15);
    f16x8 a[8];
#pragma unroll
    for (int ks = 0; ks < 8; ks++) {
        int byte = (arow * 512 + ks * 64 + (lane >> 4) * 16) ^ ((arow & 7) << 4);
        U16 r; r.u = *(const uint4*)(lds + byte);
        a[ks] = r.v;
    }
    __syncthreads();   // all waves done reading xs before epilogue overwrites

    __half* hb = (__half*)lds;            // 64x128 f16 linear
    __half* gbuf = (__half*)(lds + 16384);
    const uint4* bf = (const uint4*)w1f;

#pragma unroll
    for (int nt = 0; nt < 8; nt++) {
        f32x4 acc = {0.f, 0.f, 0.f, 0.f};
#pragma unroll
        for (int ks = 0; ks < 8; ks++) {
            U16 bw; bw.u = bf[(nt * 8 + ks) * 64 + lane];
            acc = __builtin_amdgcn_mfma_f32_16x16x32_f16(a[ks], bw.v, acc, 0, 0, 0);
        }
        int colb = nt * 16 + (lane & 15);
        float bias = b1[colb];
#pragma unroll
        for (int r = 0; r < 4; r++) {
            int row = wv * 16 + (lane >> 4) * 4 + r;
            int gn = nb + row;
            float dv = (gn < NN) ? dinv[gn] : 0.f;
            float v = fmaxf(acc[r] + bias, 0.f);
            hb[row * HD + colb] = __float2half(v);
            gbuf[row * HD + colb] = __float2half(dv * v);
        }
    }
    __syncthreads();

    // coalesced copy-out
#pragma unroll
    for (int it = 0; it < 4; it++) {
        int c = it * 256 + tid;          // 1024 chunks of 16B per buffer
        int row = c >> 4;
        if (nb + row < NN) {
            *(uint4*)((char*)h0h + (size_t)nb * 256 + c * 16) = *(uint4*)((char*)hb + c * 16);
            *(uint4*)((char*)g0 + (size_t)nb * 256 + c * 16) = *(uint4*)((char*)gbuf + c * 16);
        }
    }
}

// ---------------- GCNII layer ----------------
// gather: one 16-lane group owns one node; col slice staged in LDS; work-stealing.
// Block-uniform STAGED fast path removes per-edge ECAP guards.
// GEMM: h = relu(comb @ W') with W' = (1-b)I + bW pre-folded.
// OUT_MODE 0: gOut = f16(dinv*h) contiguous   OUT_MODE 1: hOut = f16 h, 512B-strided

template <int OUT_MODE>
__global__ __launch_bounds__(256, 8) void k_layer(const __half2* __restrict__ gIn,
                                                  __half* __restrict__ gOutH,
                                                  __half* __restrict__ hOut7,
                                                  const __half2* __restrict__ h0,
                                                  const float* __restrict__ dinv,
                                                  const int* __restrict__ rowp,
                                                  const int* __restrict__ col,
                                                  const __half* __restrict__ wfL) {
    __shared__ __half csh[NPB * HD];    // 8 KB: comb f16, swizzled; reused for output
    __shared__ int sCol[ECAP];          // 3 KB staged col indices
    __shared__ int sRowp[NPB + 1];
    __shared__ int sCtr;
    int tid = threadIdx.x;
    int nb = blockIdx.x * NPB;
    int lane = tid & 63;
    int sub = lane & 15;                // lane within 16-lane group
    const uint4* g4 = (const uint4*)gIn;   // 16 chunks of 16B per row
    const uint4* h4 = (const uint4*)h0;

    if (tid == 0) sCtr = 0;
    if (tid <= NPB) sRowp[tid] = rowp[nb + tid];
    __syncthreads();
    int base = sRowp[0];
    int total = sRowp[NPB] - base;
    int stct = total < ECAP ? total : ECAP;
    for (int i = tid; i < stct; i += 256) sCol[i] = col[base + i];
    __syncthreads();

    auto steal = [&](auto staged_c) {
        constexpr bool STAGED = decltype(staged_c)::value;
        while (true) {
            int nl;
            if (sub == 0) nl = atomicAdd(&sCtr, 1);
            nl = __shfl(nl, lane & 48);     // broadcast from group leader
            if (nl >= NPB) break;
            int n = nb + nl;
            int beg = sRowp[nl] - base, end = sRowp[nl + 1] - base;

            // issue self-row + h0-row + dinv early so they overlap the edge loop
            U16 sv; sv.u = g4[(size_t)n * 16 + sub];
            U16 hv; hv.u = h4[(size_t)n * 16 + sub];
            float dv = dinv[n];

            float acc[8];
#pragma unroll
            for (int q = 0; q < 4; q++) {
                float2 f = __half22float2(sv.h2[q]);
                acc[2 * q] = f.x; acc[2 * q + 1] = f.y;
            }

            int e = beg;
            for (; e + 4 <= end; e += 4) {
                int c0 = STAGED ? sCol[e]     : col[base + e];
                int c1 = STAGED ? sCol[e + 1] : col[base + e + 1];
                int c2 = STAGED ? sCol[e + 2] : col[base + e + 2];
                int c3 = STAGED ? sCol[e + 3] : col[base + e + 3];
                U16 a0, a1, a2, a3;
                a0.u = g4[(size_t)c0 * 16 + sub];
                a1.u = g4[(size_t)c1 * 16 + sub];
                a2.u = g4[(size_t)c2 * 16 + sub];
                a3.u = g4[(size_t)c3 * 16 + sub];
#pragma unroll
                for (int q = 0; q < 4; q++) {
                    float2 f0 = __half22float2(a0.h2[q]);
                    float2 f1 = __half22float2(a1.h2[q]);
                    float2 f2 = __half22float2(a2.h2[q]);
                    float2 f3 = __half22float2(a3.h2[q]);
                    acc[2 * q]     += (f0.x + f1.x) + (f2.x + f3.x);
                    acc[2 * q + 1] += (f0.y + f1.y) + (f2.y + f3.y);
                }
            }
            if (e + 2 <= end) {
                int c0 = STAGED ? sCol[e]     : col[base + e];
                int c1 = STAGED ? sCol[e + 1] : col[base + e + 1];
                U16 a0, a1;
                a0.u = g4[(size_t)c0 * 16 + sub];
                a1.u = g4[(size_t)c1 * 16 + sub];
#pragma unroll
                for (int q = 0; q < 4; q++) {
                    float2 f0 = __half22float2(a0.h2[q]);
                    float2 f1 = __half22float2(a1.h2[q]);
                    acc[2 * q]     += f0.x + f1.x;
                    acc[2 * q + 1] += f0.y + f1.y;
                }
                e += 2;
            }
            if (e < end) {
                int c0 = STAGED ? sCol[e] : col[base + e];
                U16 a0; a0.u = g4[(size_t)c0 * 16 + sub];
#pragma unroll
                for (int q = 0; q < 4; q++) {
                    float2 f0 = __half22float2(a0.h2[q]);
                    acc[2 * q] += f0.x; acc[2 * q + 1] += f0.y;
                }
            }

            U16 p;
#pragma unroll
            for (int q = 0; q < 4; q++) {
                float2 hf = __half22float2(hv.h2[q]);
                float c0 = 0.9f * dv * acc[2 * q]     + 0.1f * hf.x;
                float c1 = 0.9f * dv * acc[2 * q + 1] + 0.1f * hf.y;
                p.h2[q] = __float22half2_rn(make_float2(c0, c1));
            }
            int fbyte = (nl * 256 + sub * 16) ^ ((nl & 7) << 4);
            *(uint4*)((char*)csh + fbyte) = p.u;
        }
    };
    if (total <= ECAP) steal(std::true_type{});
    else               steal(std::false_type{});
    __syncthreads();

    // MFMA GEMM: 2 row-tiles x 8 col-tiles, 4 tiles/wave; h = relu(comb @ W')
    int wave = tid >> 6;
    int rt = wave >> 1;
    int ntb = (wave & 1) * 4;
    int arow = rt * 16 + (lane & 15);
    f16x8 a[4];
#pragma unroll
    for (int ks = 0; ks < 4; ks++) {
        int byte = (arow * 256 + ks * 64 + (lane >> 4) * 16) ^ ((arow & 7) << 4);
        U16 r; r.u = *(const uint4*)((const char*)csh + byte);
        a[ks] = r.v;
    }
    __syncthreads();   // a-frags in regs; csh reusable as output buffer

    const uint4* bf = (const uint4*)wfL;
#pragma unroll
    for (int nt2 = 0; nt2 < 4; nt2++) {
        int nt = ntb + nt2;
        f32x4 acc = {0.f, 0.f, 0.f, 0.f};
#pragma unroll
        for (int ks = 0; ks < 4; ks++) {
            U16 bw; bw.u = bf[(nt * 4 + ks) * 64 + lane];
            acc = __builtin_amdgcn_mfma_f32_16x16x32_f16(a[ks], bw.v, acc, 0, 0, 0);
        }
        int colb = nt * 16 + (lane & 15);
#pragma unroll
        for (int r = 0; r < 4; r++) {
            int row = rt * 16 + (lane >> 4) * 4 + r;
            int gn = nb + row;
            float v = fmaxf(acc[r], 0.f);
            if (OUT_MODE == 0) {
                csh[row * HD + colb] = __float2half(dinv[gn] * v);
            } else {
                csh[row * HD + colb] = __float2half(v);
            }
        }
    }
    __syncthreads();
    // coalesced copy-out: 32 rows x 256B = 512 chunks of 16B
    if (OUT_MODE == 0) {
#pragma unroll
        for (int it = 0; it < 2; it++) {
            int c = it * 256 + tid;
            *(uint4*)((char*)gOutH + (size_t)nb * 256 + c * 16) =
                *(uint4*)((char*)csh + c * 16);
        }
    } else {
        // strided: row gn occupies first 256B of a 512B slot (1:1 with k_final blocks)
#pragma unroll
        for (int it = 0; it < 2; it++) {
            int c = it * 256 + tid;
            int row = c >> 4;
            *(uint4*)((char*)hOut7 + ((size_t)(nb + row) * 512 + (c & 15) * 16)) =
                *(uint4*)((char*)csh + c * 16);
        }
    }
}

// ---------------- final (MFMA): out = h@W2+b2; vis = relu(out@Wv+bv); txt = relu(out@Wt+bt)
// hIn: f16 rows strided at 512B (first 256B of each slot), co-located with `out`.

__global__ __launch_bounds__(256) void k_final(const __half* __restrict__ hIn,
                                               const __half* __restrict__ wf,
                                               const float* __restrict__ b2,
                                               const float* __restrict__ bv,
                                               const float* __restrict__ bt,
                                               float* __restrict__ out,
                                               float* __restrict__ vis,
                                               float* __restrict__ txt) {
    __shared__ __half hs[FNPB * HD];  // 16 KB, XOR-swizzled rows
    __shared__ __half os[FNPB * HD];  // 16 KB, XOR-swizzled rows
    int tid = threadIdx.x;
    int nb = blockIdx.x * FNPB;
    int wave = tid >> 6, lane = tid & 63;

    // stage h rows (f16, strided in global) -> swizzled LDS
#pragma unroll
    for (int it = 0; it < 4; it++) {
        int idx = it * 256 + tid;            // 16B chunk; 64 rows x 16 chunks
        int row = idx >> 4, c8 = idx & 15;
        int gn = nb + row;
        uint4 p = make_uint4(0, 0, 0, 0);
        if (gn < NN)
            p = *(const uint4*)((const char*)hIn + (size_t)gn * 512 + c8 * 16);
        int byte = (row * 256 + c8 * 16) ^ ((row & 7) << 4);
        *(uint4*)((char*)hs + byte) = p;
    }
    __syncthreads();

    const uint4* bf2 = (const uint4*)(wf + (size_t)8 * HD * HD);
    const uint4* bfv = (const uint4*)(wf + (size_t)9 * HD * HD);
    const uint4* bft = (const uint4*)(wf + (size_t)10 * HD * HD);

    int arow = wave * 16 + (lane & 15);
    int kb = (lane >> 4) * 8;

    // A-frags from hs
    f16x8 a[4];
#pragma unroll
    for (int ks = 0; ks < 4; ks++) {
        int byte = (arow * 256 + (ks * 32 + kb) * 2) ^ ((arow & 7) << 4);
        U16 r; r.u = *(const uint4*)((const char*)hs + byte);
        a[ks] = r.v;
    }

    // GEMM1: out = h@W2 + b2 ; also write f16 copy into os
#pragma unroll
    for (int nt = 0; nt < 8; nt++) {
        f32x4 acc = {0.f, 0.f, 0.f, 0.f};
#pragma unroll
        for (int ks = 0; ks < 4; ks++) {
            U16 bw; bw.u = bf2[(nt * 4 + ks) * 64 + lane];
            acc = __builtin_amdgcn_mfma_f32_16x16x32_f16(a[ks], bw.v, acc, 0, 0, 0);
        }
        int c = nt * 16 + (lane & 15);
        float bias = b2[c];
#pragma unroll
        for (int r = 0; r < 4; r++) {
            int lrow = wave * 16 + (lane >> 4) * 4 + r;
            float val = acc[r] + bias;
            int gn = nb + lrow;
            if (gn < NN) out[(size_t)gn * HD + c] = val;
            int byte = (lrow * 256 + c * 2) ^ ((lrow & 7) << 4);
            *(__half*)((char*)os + byte) = __float2half(val);
        }
    }
    __syncthreads();

    // A-frags from os
    f16x8 ao[4];
#pragma unroll
    for (int ks = 0; ks < 4; ks++) {
        int byte = (arow * 256 + (ks * 32 + kb) * 2) ^ ((arow & 7) << 4);
        U16 r; r.u = *(const uint4*)((const char*)os + byte);
        ao[ks] = r.v;
    }

    // GEMM2: vis = relu(out@Wv+bv); GEMM3: txt = relu(out@Wt+bt)
#pragma unroll
    for (int nt = 0; nt < 8; nt++) {
        f32x4 accv = {0.f, 0.f, 0.f, 0.f};
        f32x4 acct = {0.f, 0.f, 0.f, 0.f};
#pragma unroll
        for (int ks = 0; ks < 4; ks++) {
            U16 bwv; bwv.u = bfv[(nt * 4 + ks) * 64 + lane];
            U16 bwt; bwt.u = bft[(nt * 4 + ks) * 64 + lane];
            accv = __builtin_amdgcn_mfma_f32_16x16x32_f16(ao[ks], bwv.v, accv, 0, 0, 0);
            acct = __builtin_amdgcn_mfma_f32_16x16x32_f16(ao[ks], bwt.v, acct, 0, 0, 0);
        }
        int c = nt * 16 + (lane & 15);
        float biasv = bv[c], biast = bt[c];
#pragma unroll
        for (int r = 0; r < 4; r++) {
            int lrow = wave * 16 + (lane >> 4) * 4 + r;
            int gn = nb + lrow;
            if (gn < NN) {
                vis[(size_t)gn * HD + c] = fmaxf(accv[r] + biasv, 0.f);
                txt[(size_t)gn * HD + c] = fmaxf(acct[r] + biast, 0.f);
            }
        }
    }
}

// ---------------- launch ----------------

extern "C" void kernel_launch(void* const* d_in, const int* in_sizes, int n_in,
                              void* d_out, int out_size, void* d_ws, size_t ws_size,
                              hipStream_t stream) {
    (void)in_sizes; (void)n_in; (void)out_size; (void)ws_size;

    const float* x    = (const float*)d_in[0];
    const int*   edge = (const int*)d_in[1];   // [2,E]: src then dst
    const float* W1   = (const float*)d_in[2];
    const float* b1   = (const float*)d_in[3];
    const float* cw   = (const float*)d_in[4]; // [8,128,128]
    const float* W2   = (const float*)d_in[5];
    const float* b2   = (const float*)d_in[6];
    const float* Wv   = (const float*)d_in[7];
    const float* bv   = (const float*)d_in[8];
    const float* Wt   = (const float*)d_in[9];
    const float* bt   = (const float*)d_in[10];

    const int* esrc = edge;
    const int* edst = edge + NE;

    // d_out regions: [0]=h7 (f16, 512B-strided) then `out`; [1]=h0(f16) then vis;
    // [2]=g ping-pong (2 x f16) then txt
    float* out0 = (float*)d_out;
    float* reg1 = out0 + (size_t)NN * HD;
    float* reg2 = reg1 + (size_t)NN * HD;

    __half* h0h = (__half*)reg1;
    __half* ga  = (__half*)reg2;
    __half* gb  = (__half*)((char*)reg2 + H16_BYTES);

    // workspace layout
    char* ws = (char*)d_ws;
    int*   deg_i = (int*)(ws + 0);          // N ints
    int*   fill  = (int*)(ws + 400000);     // N ints
    int*   rowp  = (int*)(ws + 800000);     // N+1 ints
    int*   bsums = (int*)(ws + 1200128);    // 128 ints
    int*   col   = (int*)(ws + 1200640);    // E ints
    float* dinv  = (float*)(ws + 5200640);  // N floats
    __half* wf   = (__half*)(ws + 5600640); // 11 * 128*128 halfs = 360448 B
    __half* w1f  = (__half*)(ws + 5961088); // 256*128 halfs = 65536 B

    hipMemsetAsync(ws, 0, 800000, stream);  // deg_i + fill

    k_deg<<<(NE + 255) / 256, 256, 0, stream>>>(edst, deg_i);
    k_scan1<<<NBLK_SCAN, 1024, 0, stream>>>(deg_i, rowp, bsums, dinv);
    k_scan2<<<1, 128, 0, stream>>>(bsums);
    k_scan3<<<NBLK_SCAN, 1024, 0, stream>>>(rowp, bsums);
    k_fill<<<(NE + 255) / 256, 256, 0, stream>>>(esrc, edst, rowp, fill, col);
    k_wfrag<<<208, 256, 0, stream>>>(cw, W2, Wv, Wt, W1, wf, w1f);

    k_init<<<(NN + INPB - 1) / INPB, 256, 0, stream>>>(x, w1f, b1, dinv, h0h, ga);

    // layers 0..6: f16 ping-pong (l even: ga->gb, odd: gb->ga). After l=6, g in gb.
    for (int l = 0; l < 7; l++) {
        const __half* gi = (l & 1) ? gb : ga;
        __half*       go = (l & 1) ? ga : gb;
        k_layer<0><<<NN / NPB, 256, 0, stream>>>((const __half2*)gi, go,
                                                 (__half*)nullptr, (const __half2*)h0h,
                                                 dinv, rowp, col,
                                                 wf + (size_t)l * HD * HD);
    }
    // layer 7: gb -> f16 h (strided) in region0
    k_layer<1><<<NN / NPB, 256, 0, stream>>>((const __half2*)gb, (__half*)nullptr,
                                             (__half*)out0, (const __half2*)h0h,
                                             dinv, rowp, col,
                                             wf + (size_t)7 * HD * HD);

    k_final<<<(NN + FNPB - 1) / FNPB, 256, 0, stream>>>((const __half*)out0, wf,
                                                        b2, bv, bt,
                                                        out0, reg1, reg2);
}

// Round 9
// 607.841 us; speedup vs baseline: 1.1076x; 1.0814x over previous
//
#include <hip/hip_runtime.h>
#include <hip/hip_fp16.h>
#include <math.h>

#define NN 100000
#define NE 1000000
#define IND 256
#define HD  128
#define NPB 32           // nodes per block in layer kernel (divides NN exactly)
#define FNPB 64          // nodes per block in final kernel
#define INPB 64          // nodes per block in init kernel
#define NBLK_SCAN 98     // ceil(NN/1024)
#define ECAP 768         // staged edges per block (avg 320, tail-safe + guarded)
#define H16_BYTES ((size_t)NN * HD * 2)  // 25,600,000

typedef _Float16 f16x8 __attribute__((ext_vector_type(8)));
typedef float f32x4 __attribute__((ext_vector_type(4)));

union U16 { uint4 u; __half2 h2[4]; __half h[8]; f16x8 v; };

// ---------------- CSR build ----------------

__global__ __launch_bounds__(256) void k_deg(const int* __restrict__ dst,
                                             int* __restrict__ deg) {
    int e = blockIdx.x * 256 + threadIdx.x;
    if (e < NE) atomicAdd(&deg[dst[e]], 1);
}

__global__ __launch_bounds__(1024) void k_scan1(const int* __restrict__ deg,
                                                int* __restrict__ rowp,
                                                int* __restrict__ bsums,
                                                float* __restrict__ dinv) {
    __shared__ int s[1024];
    int t = threadIdx.x;
    int i = blockIdx.x * 1024 + t;
    int v = (i < NN) ? deg[i] : 0;
    if (i < NN) dinv[i] = rsqrtf((float)(v + 1));  // +1 self-loop
    s[t] = v;
    __syncthreads();
    for (int off = 1; off < 1024; off <<= 1) {
        int u = (t >= off) ? s[t - off] : 0;
        __syncthreads();
        s[t] += u;
        __syncthreads();
    }
    if (i < NN) rowp[i] = s[t] - v;
    if (t == 1023) bsums[blockIdx.x] = s[1023];
}

__global__ __launch_bounds__(128) void k_scan2(int* __restrict__ bsums) {
    __shared__ int s[128];
    int t = threadIdx.x;
    int v = (t < NBLK_SCAN) ? bsums[t] : 0;
    s[t] = v;
    __syncthreads();
    for (int off = 1; off < 128; off <<= 1) {
        int u = (t >= off) ? s[t - off] : 0;
        __syncthreads();
        s[t] += u;
        __syncthreads();
    }
    if (t < NBLK_SCAN) bsums[t] = s[t] - v;
}

__global__ __launch_bounds__(1024) void k_scan3(int* __restrict__ rowp,
                                                const int* __restrict__ bsums) {
    int i = blockIdx.x * 1024 + threadIdx.x;
    if (i < NN) rowp[i] += bsums[i >> 10];
    if (i == 0) rowp[NN] = NE;
}

__global__ __launch_bounds__(256) void k_fill(const int* __restrict__ src,
                                              const int* __restrict__ dst,
                                              const int* __restrict__ rowp,
                                              int* __restrict__ fill,
                                              int* __restrict__ col) {
    int e = blockIdx.x * 256 + threadIdx.x;
    if (e < NE) {
        int d = dst[e];
        int pos = rowp[d] + atomicAdd(&fill[d], 1);
        col[pos] = src[e];
    }
}

// ---------------- weight fragment pre-pack (all 12 matrices) ----------------
// KS=4 layout: wf[m][((nt*4+ks)*64+lane)*8+j] = f16(W'[ks*32+(lane>>4)*8+j][nt*16+(lane&15)])
// For m<8 (conv layers) the residual is folded in: W' = beta*W + (1-beta)*I.
// blocks 176..207: W1 [256,128], KS=8 into w1f.

__global__ __launch_bounds__(256) void k_wfrag(const float* __restrict__ cw,
                                               const float* __restrict__ W2,
                                               const float* __restrict__ Wv,
                                               const float* __restrict__ Wt,
                                               const float* __restrict__ W1,
                                               __half* __restrict__ wf,
                                               __half* __restrict__ w1f) {
    int bid = blockIdx.x;
    if (bid < 176) {
        int m = bid >> 4;     // matrix 0..10
        int blk = bid & 15;
        const float* W = (m < 8) ? (cw + (size_t)m * HD * HD)
                                 : (m == 8 ? W2 : (m == 9 ? Wv : Wt));
        int i = (blk * 256 + threadIdx.x) * 4;   // element index k*128+col
        float4 v = *(const float4*)&W[i];
        int k = i >> 7, col0 = i & 127;
        float vv[4] = {v.x, v.y, v.z, v.w};
        float beta = 1.f, omb = 0.f;
        if (m < 8) {
            beta = logf(0.5f / (float)(m + 1) + 1.0f);
            omb = 1.f - beta;
        }
        __half* dstm = wf + (size_t)m * HD * HD;
        int ks = k >> 5, laneK = ((k >> 3) & 3) * 16, j = k & 7;
#pragma unroll
        for (int t = 0; t < 4; t++) {
            int col = col0 + t;
            float val = beta * vv[t] + ((k == col) ? omb : 0.f);
            int nt = col >> 4;
            int lane = laneK + (col & 15);
            dstm[((nt * 4 + ks) * 64 + lane) * 8 + j] = __float2half(val);
        }
    } else {
        int blk = bid - 176;  // 0..31
        int i = (blk * 256 + threadIdx.x) * 4;   // k*128+col, total 32768
        float4 v = *(const float4*)&W1[i];
        int k = i >> 7, col0 = i & 127;
        float vv[4] = {v.x, v.y, v.z, v.w};
        int ks = k >> 5, laneK = ((k >> 3) & 3) * 16, j = k & 7;
#pragma unroll
        for (int t = 0; t < 4; t++) {
            int col = col0 + t;
            int nt = col >> 4;
            int lane = laneK + (col & 15);
            w1f[((nt * 8 + ks) * 64 + lane) * 8 + j] = __float2half(vv[t]);
        }
    }
}

// ---------------- initial transform (MFMA): h0 = relu(x@W1+b1) f16, g0 = dinv*h0 f16 ----

__global__ __launch_bounds__(256) void k_init(const float* __restrict__ x,
                                              const __half* __restrict__ w1f,
                                              const float* __restrict__ b1,
                                              const float* __restrict__ dinv,
                                              __half* __restrict__ h0h,
                                              __half* __restrict__ g0) {
    __shared__ char lds[32768];     // xs (swizzled f16 64x256), later hb/gb
    int tid = threadIdx.x;
    int nb = blockIdx.x * INPB;
    int wv = tid >> 6, lane = tid & 63;

    // stage x -> f16 swizzled (rows of 512B)
#pragma unroll
    for (int it = 0; it < 8; it++) {
        int c = it * 256 + tid;          // chunk of 8 floats: 64 rows x 32 chunks
        int row = c >> 5, k8 = c & 31;
        int gn = nb + row;
        float4 a = make_float4(0.f, 0.f, 0.f, 0.f), b = a;
        if (gn < NN) {
            a = *(const float4*)&x[(size_t)gn * IND + k8 * 8];
            b = *(const float4*)&x[(size_t)gn * IND + k8 * 8 + 4];
        }
        U16 p;
        p.h[0] = __float2half(a.x); p.h[1] = __float2half(a.y);
        p.h[2] = __float2half(a.z); p.h[3] = __float2half(a.w);
        p.h[4] = __float2half(b.x); p.h[5] = __float2half(b.y);
        p.h[6] = __float2half(b.z); p.h[7] = __float2half(b.w);
        int byte = (row * 512 + k8 * 16) ^ ((row & 7) << 4);
        *(uint4*)(lds + byte) = p.u;
    }
    __syncthreads();

    // A-frags: wave = row-tile
    int arow = wv * 16 + (lane & 15);
    f16x8 a[8];
#pragma unroll
    for (int ks = 0; ks < 8; ks++) {
        int byte = (arow * 512 + ks * 64 + (lane >> 4) * 16) ^ ((arow & 7) << 4);
        U16 r; r.u = *(const uint4*)(lds + byte);
        a[ks] = r.v;
    }
    __syncthreads();   // all waves done reading xs before epilogue overwrites

    __half* hb = (__half*)lds;            // 64x128 f16 linear
    __half* gbuf = (__half*)(lds + 16384);
    const uint4* bf = (const uint4*)w1f;

#pragma unroll
    for (int nt = 0; nt < 8; nt++) {
        f32x4 acc = {0.f, 0.f, 0.f, 0.f};
#pragma unroll
        for (int ks = 0; ks < 8; ks++) {
            U16 bw; bw.u = bf[(nt * 8 + ks) * 64 + lane];
            acc = __builtin_amdgcn_mfma_f32_16x16x32_f16(a[ks], bw.v, acc, 0, 0, 0);
        }
        int colb = nt * 16 + (lane & 15);
        float bias = b1[colb];
#pragma unroll
        for (int r = 0; r < 4; r++) {
            int row = wv * 16 + (lane >> 4) * 4 + r;
            int gn = nb + row;
            float dv = (gn < NN) ? dinv[gn] : 0.f;
            float v = fmaxf(acc[r] + bias, 0.f);
            hb[row * HD + colb] = __float2half(v);
            gbuf[row * HD + colb] = __float2half(dv * v);
        }
    }
    __syncthreads();

    // coalesced copy-out
#pragma unroll
    for (int it = 0; it < 4; it++) {
        int c = it * 256 + tid;          // 1024 chunks of 16B per buffer
        int row = c >> 4;
        if (nb + row < NN) {
            *(uint4*)((char*)h0h + (size_t)nb * 256 + c * 16) = *(uint4*)((char*)hb + c * 16);
            *(uint4*)((char*)g0 + (size_t)nb * 256 + c * 16) = *(uint4*)((char*)gbuf + c * 16);
        }
    }
}

// ---------------- GCNII layer (round-6 proven shape) ----------------
// gather: one 16-lane group owns one node; col slice staged in LDS; work-stealing.
// GEMM: h = relu(comb @ W') with W' = (1-b)I + bW pre-folded.
// OUT_MODE 0: gOut = f16(dinv*h) contiguous   OUT_MODE 1: hOut = f16 h, 512B-strided

template <int OUT_MODE>
__global__ __launch_bounds__(256) void k_layer(const __half2* __restrict__ gIn,
                                               __half* __restrict__ gOutH,
                                               __half* __restrict__ hOut7,
                                               const __half2* __restrict__ h0,
                                               const float* __restrict__ dinv,
                                               const int* __restrict__ rowp,
                                               const int* __restrict__ col,
                                               const __half* __restrict__ wfL) {
    __shared__ __half csh[NPB * HD];    // 8 KB: comb f16, swizzled; reused for output
    __shared__ int sCol[ECAP];          // 3 KB staged col indices
    __shared__ int sRowp[NPB + 1];
    __shared__ int sCtr;
    int tid = threadIdx.x;
    int nb = blockIdx.x * NPB;
    int lane = tid & 63;
    int sub = lane & 15;                // lane within 16-lane group
    const uint4* g4 = (const uint4*)gIn;   // 16 chunks of 16B per row
    const uint4* h4 = (const uint4*)h0;

    if (tid == 0) sCtr = 0;
    if (tid <= NPB) sRowp[tid] = rowp[nb + tid];
    __syncthreads();
    int base = sRowp[0];
    int total = sRowp[NPB] - base;
    int stct = total < ECAP ? total : ECAP;
    for (int i = tid; i < stct; i += 256) sCol[i] = col[base + i];
    __syncthreads();

    while (true) {
        int nl;
        if (sub == 0) nl = atomicAdd(&sCtr, 1);
        nl = __shfl(nl, lane & 48);     // broadcast from group leader
        if (nl >= NPB) break;
        int n = nb + nl;
        int beg = sRowp[nl] - base, end = sRowp[nl + 1] - base;

        // self-loop init
        float acc[8];
        {
            U16 v; v.u = g4[(size_t)n * 16 + sub];
#pragma unroll
            for (int q = 0; q < 4; q++) {
                float2 f = __half22float2(v.h2[q]);
                acc[2 * q] = f.x; acc[2 * q + 1] = f.y;
            }
        }

        int e = beg;
        for (; e + 4 <= end; e += 4) {
            int c0 = (e     < ECAP) ? sCol[e]     : col[base + e];
            int c1 = (e + 1 < ECAP) ? sCol[e + 1] : col[base + e + 1];
            int c2 = (e + 2 < ECAP) ? sCol[e + 2] : col[base + e + 2];
            int c3 = (e + 3 < ECAP) ? sCol[e + 3] : col[base + e + 3];
            U16 a0, a1, a2, a3;
            a0.u = g4[(size_t)c0 * 16 + sub];
            a1.u = g4[(size_t)c1 * 16 + sub];
            a2.u = g4[(size_t)c2 * 16 + sub];
            a3.u = g4[(size_t)c3 * 16 + sub];
#pragma unroll
            for (int q = 0; q < 4; q++) {
                float2 f0 = __half22float2(a0.h2[q]);
                float2 f1 = __half22float2(a1.h2[q]);
                float2 f2 = __half22float2(a2.h2[q]);
                float2 f3 = __half22float2(a3.h2[q]);
                acc[2 * q]     += (f0.x + f1.x) + (f2.x + f3.x);
                acc[2 * q + 1] += (f0.y + f1.y) + (f2.y + f3.y);
            }
        }
        if (e + 2 <= end) {
            int c0 = (e     < ECAP) ? sCol[e]     : col[base + e];
            int c1 = (e + 1 < ECAP) ? sCol[e + 1] : col[base + e + 1];
            U16 a0, a1;
            a0.u = g4[(size_t)c0 * 16 + sub];
            a1.u = g4[(size_t)c1 * 16 + sub];
#pragma unroll
            for (int q = 0; q < 4; q++) {
                float2 f0 = __half22float2(a0.h2[q]);
                float2 f1 = __half22float2(a1.h2[q]);
                acc[2 * q]     += f0.x + f1.x;
                acc[2 * q + 1] += f0.y + f1.y;
            }
            e += 2;
        }
        if (e < end) {
            int c0 = (e < ECAP) ? sCol[e] : col[base + e];
            U16 a0; a0.u = g4[(size_t)c0 * 16 + sub];
#pragma unroll
            for (int q = 0; q < 4; q++) {
                float2 f0 = __half22float2(a0.h2[q]);
                acc[2 * q] += f0.x; acc[2 * q + 1] += f0.y;
            }
        }

        float dv = dinv[n];
        U16 hv; hv.u = h4[(size_t)n * 16 + sub];
        U16 p;
#pragma unroll
        for (int q = 0; q < 4; q++) {
            float2 hf = __half22float2(hv.h2[q]);
            float c0 = 0.9f * dv * acc[2 * q]     + 0.1f * hf.x;
            float c1 = 0.9f * dv * acc[2 * q + 1] + 0.1f * hf.y;
            p.h2[q] = __float22half2_rn(make_float2(c0, c1));
        }
        int fbyte = (nl * 256 + sub * 16) ^ ((nl & 7) << 4);
        *(uint4*)((char*)csh + fbyte) = p.u;
    }
    __syncthreads();

    // MFMA GEMM: 2 row-tiles x 8 col-tiles, 4 tiles/wave; h = relu(comb @ W')
    int wave = tid >> 6;
    int rt = wave >> 1;
    int ntb = (wave & 1) * 4;
    int arow = rt * 16 + (lane & 15);
    f16x8 a[4];
#pragma unroll
    for (int ks = 0; ks < 4; ks++) {
        int byte = (arow * 256 + ks * 64 + (lane >> 4) * 16) ^ ((arow & 7) << 4);
        U16 r; r.u = *(const uint4*)((const char*)csh + byte);
        a[ks] = r.v;
    }
    __syncthreads();   // a-frags in regs; csh reusable as output buffer

    const uint4* bf = (const uint4*)wfL;
#pragma unroll
    for (int nt2 = 0; nt2 < 4; nt2++) {
        int nt = ntb + nt2;
        f32x4 acc = {0.f, 0.f, 0.f, 0.f};
#pragma unroll
        for (int ks = 0; ks < 4; ks++) {
            U16 bw; bw.u = bf[(nt * 4 + ks) * 64 + lane];
            acc = __builtin_amdgcn_mfma_f32_16x16x32_f16(a[ks], bw.v, acc, 0, 0, 0);
        }
        int colb = nt * 16 + (lane & 15);
#pragma unroll
        for (int r = 0; r < 4; r++) {
            int row = rt * 16 + (lane >> 4) * 4 + r;
            int gn = nb + row;
            float v = fmaxf(acc[r], 0.f);
            if (OUT_MODE == 0) {
                csh[row * HD + colb] = __float2half(dinv[gn] * v);
            } else {
                csh[row * HD + colb] = __float2half(v);
            }
        }
    }
    __syncthreads();
    // coalesced copy-out: 32 rows x 256B = 512 chunks of 16B
    if (OUT_MODE == 0) {
#pragma unroll
        for (int it = 0; it < 2; it++) {
            int c = it * 256 + tid;
            *(uint4*)((char*)gOutH + (size_t)nb * 256 + c * 16) =
                *(uint4*)((char*)csh + c * 16);
        }
    } else {
        // strided: row gn occupies first 256B of a 512B slot (1:1 with k_final blocks)
#pragma unroll
        for (int it = 0; it < 2; it++) {
            int c = it * 256 + tid;
            int row = c >> 4;
            *(uint4*)((char*)hOut7 + ((size_t)(nb + row) * 512 + (c & 15) * 16)) =
                *(uint4*)((char*)csh + c * 16);
        }
    }
}

// ---------------- final (MFMA): out = h@W2+b2; vis = relu(out@Wv+bv); txt = relu(out@Wt+bt)
// hIn: f16 rows strided at 512B (first 256B of each slot), co-located with `out`.

__global__ __launch_bounds__(256) void k_final(const __half* __restrict__ hIn,
                                               const __half* __restrict__ wf,
                                               const float* __restrict__ b2,
                                               const float* __restrict__ bv,
                                               const float* __restrict__ bt,
                                               float* __restrict__ out,
                                               float* __restrict__ vis,
                                               float* __restrict__ txt) {
    __shared__ __half hs[FNPB * HD];  // 16 KB, XOR-swizzled rows
    __shared__ __half os[FNPB * HD];  // 16 KB, XOR-swizzled rows
    int tid = threadIdx.x;
    int nb = blockIdx.x * FNPB;
    int wave = tid >> 6, lane = tid & 63;

    // stage h rows (f16, strided in global) -> swizzled LDS
#pragma unroll
    for (int it = 0; it < 4; it++) {
        int idx = it * 256 + tid;            // 16B chunk; 64 rows x 16 chunks
        int row = idx >> 4, c8 = idx & 15;
        int gn = nb + row;
        uint4 p = make_uint4(0, 0, 0, 0);
        if (gn < NN)
            p = *(const uint4*)((const char*)hIn + (size_t)gn * 512 + c8 * 16);
        int byte = (row * 256 + c8 * 16) ^ ((row & 7) << 4);
        *(uint4*)((char*)hs + byte) = p;
    }
    __syncthreads();

    const uint4* bf2 = (const uint4*)(wf + (size_t)8 * HD * HD);
    const uint4* bfv = (const uint4*)(wf + (size_t)9 * HD * HD);
    const uint4* bft = (const uint4*)(wf + (size_t)10 * HD * HD);

    int arow = wave * 16 + (lane & 15);
    int kb = (lane >> 4) * 8;

    // A-frags from hs
    f16x8 a[4];
#pragma unroll
    for (int ks = 0; ks < 4; ks++) {
        int byte = (arow * 256 + (ks * 32 + kb) * 2) ^ ((arow & 7) << 4);
        U16 r; r.u = *(const uint4*)((const char*)hs + byte);
        a[ks] = r.v;
    }

    // GEMM1: out = h@W2 + b2 ; also write f16 copy into os
#pragma unroll
    for (int nt = 0; nt < 8; nt++) {
        f32x4 acc = {0.f, 0.f, 0.f, 0.f};
#pragma unroll
        for (int ks = 0; ks < 4; ks++) {
            U16 bw; bw.u = bf2[(nt * 4 + ks) * 64 + lane];
            acc = __builtin_amdgcn_mfma_f32_16x16x32_f16(a[ks], bw.v, acc, 0, 0, 0);
        }
        int c = nt * 16 + (lane & 15);
        float bias = b2[c];
#pragma unroll
        for (int r = 0; r < 4; r++) {
            int lrow = wave * 16 + (lane >> 4) * 4 + r;
            float val = acc[r] + bias;
            int gn = nb + lrow;
            if (gn < NN) out[(size_t)gn * HD + c] = val;
            int byte = (lrow * 256 + c * 2) ^ ((lrow & 7) << 4);
            *(__half*)((char*)os + byte) = __float2half(val);
        }
    }
    __syncthreads();

    // A-frags from os
    f16x8 ao[4];
#pragma unroll
    for (int ks = 0; ks < 4; ks++) {
        int byte = (arow * 256 + (ks * 32 + kb) * 2) ^ ((arow & 7) << 4);
        U16 r; r.u = *(const uint4*)((const char*)os + byte);
        ao[ks] = r.v;
    }

    // GEMM2: vis = relu(out@Wv+bv); GEMM3: txt = relu(out@Wt+bt)
#pragma unroll
    for (int nt = 0; nt < 8; nt++) {
        f32x4 accv = {0.f, 0.f, 0.f, 0.f};
        f32x4 acct = {0.f, 0.f, 0.f, 0.f};
#pragma unroll
        for (int ks = 0; ks < 4; ks++) {
            U16 bwv; bwv.u = bfv[(nt * 4 + ks) * 64 + lane];
            U16 bwt; bwt.u = bft[(nt * 4 + ks) * 64 + lane];
            accv = __builtin_amdgcn_mfma_f32_16x16x32_f16(ao[ks], bwv.v, accv, 0, 0, 0);
            acct = __builtin_amdgcn_mfma_f32_16x16x32_f16(ao[ks], bwt.v, acct, 0, 0, 0);
        }
        int c = nt * 16 + (lane & 15);
        float biasv = bv[c], biast = bt[c];
#pragma unroll
        for (int r = 0; r < 4; r++) {
            int lrow = wave * 16 + (lane >> 4) * 4 + r;
            int gn = nb + lrow;
            if (gn < NN) {
                vis[(size_t)gn * HD + c] = fmaxf(accv[r] + biasv, 0.f);
                txt[(size_t)gn * HD + c] = fmaxf(acct[r] + biast, 0.f);
            }
        }
    }
}

// ---------------- launch ----------------

extern "C" void kernel_launch(void* const* d_in, const int* in_sizes, int n_in,
                              void* d_out, int out_size, void* d_ws, size_t ws_size,
                              hipStream_t stream) {
    (void)in_sizes; (void)n_in; (void)out_size; (void)ws_size;

    const float* x    = (const float*)d_in[0];
    const int*   edge = (const int*)d_in[1];   // [2,E]: src then dst
    const float* W1   = (const float*)d_in[2];
    const float* b1   = (const float*)d_in[3];
    const float* cw   = (const float*)d_in[4]; // [8,128,128]
    const float* W2   = (const float*)d_in[5];
    const float* b2   = (const float*)d_in[6];
    const float* Wv   = (const float*)d_in[7];
    const float* bv   = (const float*)d_in[8];
    const float* Wt   = (const float*)d_in[9];
    const float* bt   = (const float*)d_in[10];

    const int* esrc = edge;
    const int* edst = edge + NE;

    // d_out regions: [0]=h7 (f16, 512B-strided) then `out`; [1]=h0(f16) then vis;
    // [2]=g ping-pong (2 x f16) then txt
    float* out0 = (float*)d_out;
    float* reg1 = out0 + (size_t)NN * HD;
    float* reg2 = reg1 + (size_t)NN * HD;

    __half* h0h = (__half*)reg1;
    __half* ga  = (__half*)reg2;
    __half* gb  = (__half*)((char*)reg2 + H16_BYTES);

    // workspace layout
    char* ws = (char*)d_ws;
    int*   deg_i = (int*)(ws + 0);          // N ints
    int*   fill  = (int*)(ws + 400000);     // N ints
    int*   rowp  = (int*)(ws + 800000);     // N+1 ints
    int*   bsums = (int*)(ws + 1200128);    // 128 ints
    int*   col   = (int*)(ws + 1200640);    // E ints
    float* dinv  = (float*)(ws + 5200640);  // N floats
    __half* wf   = (__half*)(ws + 5600640); // 11 * 128*128 halfs = 360448 B
    __half* w1f  = (__half*)(ws + 5961088); // 256*128 halfs = 65536 B

    hipMemsetAsync(ws, 0, 800000, stream);  // deg_i + fill

    k_deg<<<(NE + 255) / 256, 256, 0, stream>>>(edst, deg_i);
    k_scan1<<<NBLK_SCAN, 1024, 0, stream>>>(deg_i, rowp, bsums, dinv);
    k_scan2<<<1, 128, 0, stream>>>(bsums);
    k_scan3<<<NBLK_SCAN, 1024, 0, stream>>>(rowp, bsums);
    k_fill<<<(NE + 255) / 256, 256, 0, stream>>>(esrc, edst, rowp, fill, col);
    k_wfrag<<<208, 256, 0, stream>>>(cw, W2, Wv, Wt, W1, wf, w1f);

    k_init<<<(NN + INPB - 1) / INPB, 256, 0, stream>>>(x, w1f, b1, dinv, h0h, ga);

    // layers 0..6: f16 ping-pong (l even: ga->gb, odd: gb->ga). After l=6, g in gb.
    for (int l = 0; l < 7; l++) {
        const __half* gi = (l & 1) ? gb : ga;
        __half*       go = (l & 1) ? ga : gb;
        k_layer<0><<<NN / NPB, 256, 0, stream>>>((const __half2*)gi, go,
                                                 (__half*)nullptr, (const __half2*)h0h,
                                                 dinv, rowp, col,
                                                 wf + (size_t)l * HD * HD);
    }
    // layer 7: gb -> f16 h (strided) in region0
    k_layer<1><<<NN / NPB, 256, 0, stream>>>((const __half2*)gb, (__half*)nullptr,
                                             (__half*)out0, (const __half2*)h0h,
                                             dinv, rowp, col,
                                             wf + (size_t)7 * HD * HD);

    k_final<<<(NN + FNPB - 1) / FNPB, 256, 0, stream>>>((const __half*)out0, wf,
                                                        b2, bv, bt,
                                                        out0, reg1, reg2);
}